// Round 5
// baseline (67782.019 us; speedup 1.0000x reference)
//
#include <hip/hip_runtime.h>
#include <stdint.h>
#include <stddef.h>

#define T_ 512
#define B_ 128
#define D_ 400
#define H_ 400
#define HP 416
#define GP 1664            // 4*HP (per-dir padded gate dim)
#define NW 3328            // both dirs stacked
#define K0P 448            // padded K for layer 0 GEMM
#define K12P 832           // padded K for layers 1,2 GEMM

// ---- rec2 LDS layout ----
#define HROW 424                              // padded h row stride (shorts)
#define HB_BYTES (2*16*HROW*2)                // 27136
#define GXL_OFF  HB_BYTES
#define GXL_BYTES (13*32*64*4)                // 106496
#define LDS2 (GXL_OFF + GXL_BYTES)            // 133632

typedef __attribute__((ext_vector_type(8))) __bf16 bf16x8;
typedef __attribute__((ext_vector_type(4))) float f32x4;
typedef __attribute__((ext_vector_type(8))) unsigned short us8;

__device__ __forceinline__ unsigned short f2bf(float f){
  unsigned u = __builtin_bit_cast(unsigned, f);
  u = (u + 0x7FFFu + ((u >> 16) & 1u)) >> 16;
  return (unsigned short)u;
}
__device__ __forceinline__ float bf2f(unsigned short s){
  unsigned u = ((unsigned)s) << 16;
  return __builtin_bit_cast(float, u);
}
__device__ __forceinline__ float sigm(float x){ return 1.f / (1.f + __expf(-x)); }
__device__ __forceinline__ float tanh_f(float x){
  float ax = fabsf(x);
  float e = __expf(-2.f * ax);
  float t = (1.f - e) / (1.f + e);
  return x < 0.f ? -t : t;
}
__device__ __forceinline__ void store_gx(float* p, float v){ *p = v; }
__device__ __forceinline__ void store_gx(unsigned short* p, float v){ *p = f2bf(v); }

// ======================= prep kernels =======================
__global__ void k_conv_x0(const float* __restrict__ x, unsigned short* __restrict__ xa){
  const size_t i = (size_t)blockIdx.x*256 + threadIdx.x;
  if (i >= (size_t)T_*B_*K0P) return;
  const int k = (int)(i % K0P);
  const size_t tb = i / K0P;
  xa[i] = f2bf(k < D_ ? x[tb*D_ + k] : 0.f);
}

__global__ void k_prep_wih(const float* __restrict__ wf, const float* __restrict__ wb,
                           int K, int mode, unsigned short* __restrict__ dst){
  const size_t i = (size_t)blockIdx.x*256 + threadIdx.x;
  if (i >= (size_t)NW*K) return;
  const int k = (int)(i % K);
  const int n = (int)(i / K);
  const int d = n / GP, ng = n % GP, g = ng / HP, r = ng % HP;
  const float* Wsrc = d ? wb : wf;
  float v = 0.f;
  if (r < H_){
    if (mode == 0){
      if (k < D_) v = Wsrc[(size_t)(g*H_ + r)*D_ + k];
    } else {
      int ks = (k < 400) ? k : ((k >= 416 && k < 816) ? (k - 16) : -1);
      if (ks >= 0) v = Wsrc[(size_t)(g*H_ + r)*800 + ks];
    }
  }
  dst[i] = f2bf(v);
}

// Whh -> per-(dir,wave,frag) MFMA B-fragment blob: [2][13][104][64 lanes] us8
// frag fi = (g*2+cf)*13 + kk ; lane holds col w*32+cf*16+(l&15), k = kk*32+(l>>4)*8+e
__global__ void k_prep_whh2(const float* __restrict__ wf, const float* __restrict__ wb,
                            unsigned short* __restrict__ dst){
  const size_t i = (size_t)blockIdx.x*256 + threadIdx.x;
  if (i >= (size_t)2*13*104*64) return;
  const int lane = (int)(i & 63);
  size_t q = i >> 6;
  const int fi = (int)(q % 104); q /= 104;
  const int w = (int)(q % 13);
  const int dir = (int)(q / 13);
  const int g = fi / 26, rem = fi % 26, cf = rem / 13, kk = rem % 13;
  const int c = w*32 + cf*16 + (lane & 15);
  const int k0 = kk*32 + (lane >> 4)*8;
  const float* W = dir ? wb : wf;
  unsigned short v[8];
  #pragma unroll
  for (int e = 0; e < 8; ++e){
    const int k = k0 + e;
    const float x = (c < H_ && k < H_) ? W[(size_t)(g*H_ + c)*H_ + k] : 0.f;
    v[e] = f2bf(x);
  }
  *(us8*)(dst + i*8) = *(const us8*)v;
}

__global__ void k_prep_bias(const float* __restrict__ bsf, const float* __restrict__ bsb,
                            float* __restrict__ dst){
  const int n = blockIdx.x*256 + threadIdx.x;
  if (n >= NW) return;
  const int d = n / GP, ng = n % GP, g = ng / HP, r = ng % HP;
  dst[n] = (r < H_) ? (d ? bsb : bsf)[g*H_ + r] : 0.f;
}

// ======================= gx GEMM =======================
// Output layout (per element): [t][grp][dir][w][g][cf][bb(16)][li(16)]
template<typename GXT>
__global__ __launch_bounds__(256) void gemm_gx(
    const unsigned short* __restrict__ X, int lda, int K,
    const unsigned short* __restrict__ W,
    const float* __restrict__ bias,
    GXT* __restrict__ gx,
    const int* __restrict__ lens)
{
  const int t = blockIdx.y;
  if (t >= lens[0]) return;
  const int n0 = blockIdx.x * 128;
  __shared__ unsigned short As[128*64];
  __shared__ unsigned short Bs[128*64];
  const int tid = threadIdx.x;
  const int l = tid & 63;
  const int w = tid >> 6;
  const int wm = (w >> 1) * 64, wn = (w & 1) * 64;
  const int lr = l & 15, lk = l >> 4;
  f32x4 acc[4][4];
  #pragma unroll
  for (int i = 0; i < 4; ++i)
    #pragma unroll
    for (int j = 0; j < 4; ++j) acc[i][j] = (f32x4){0.f,0.f,0.f,0.f};

  const unsigned short* Xb = X + (size_t)t * B_ * lda;
  const int r_ = tid >> 3, s_ = (tid & 7) * 8;

  for (int k0 = 0; k0 < K; k0 += 64){
    us8 va[4], vb[4];
    #pragma unroll
    for (int i = 0; i < 4; ++i){
      const int r = i*32 + r_;
      va[i] = *(const us8*)(Xb + (size_t)r*lda + k0 + s_);
      vb[i] = *(const us8*)(W  + (size_t)(n0 + r)*K + k0 + s_);
    }
    __syncthreads();
    #pragma unroll
    for (int i = 0; i < 4; ++i){
      const int r = i*32 + r_;
      *(us8*)&As[r*64 + s_] = va[i];
      *(us8*)&Bs[r*64 + s_] = vb[i];
    }
    __syncthreads();
    #pragma unroll
    for (int kk = 0; kk < 2; ++kk){
      bf16x8 af[4], bfr[4];
      #pragma unroll
      for (int mi = 0; mi < 4; ++mi)
        af[mi] = __builtin_bit_cast(bf16x8, *(const us8*)&As[(wm + mi*16 + lr)*64 + kk*32 + lk*8]);
      #pragma unroll
      for (int ni = 0; ni < 4; ++ni)
        bfr[ni] = __builtin_bit_cast(bf16x8, *(const us8*)&Bs[(wn + ni*16 + lr)*64 + kk*32 + lk*8]);
      #pragma unroll
      for (int mi = 0; mi < 4; ++mi)
        #pragma unroll
        for (int ni = 0; ni < 4; ++ni)
          acc[mi][ni] = __builtin_amdgcn_mfma_f32_16x16x32_bf16(af[mi], bfr[ni], acc[mi][ni], 0, 0, 0);
    }
  }
  // epilogue: scatter into rec-friendly layout (runs of 16 floats over lr)
  #pragma unroll
  for (int ni = 0; ni < 4; ++ni){
    const int colb = n0 + wn + ni*16;          // lane-uniform, multiple of 16
    const float bv = bias[colb + lr];
    const int dir = colb >= GP ? 1 : 0;
    const int cgb = colb - dir*GP;
    const int g  = cgb >= 1248 ? 3 : cgb >= 832 ? 2 : cgb >= 416 ? 1 : 0;
    const int cb = cgb - g*416;
    const int w2 = cb >> 5, cf = (cb >> 4) & 1;
    #pragma unroll
    for (int mi = 0; mi < 4; ++mi){
      const int bbase = wm + mi*16;
      const int grp2 = bbase >> 4;
      const size_t base =
          ((((((size_t)t*8 + grp2)*2 + dir)*13 + w2)*4 + g)*2 + cf)*16;
      #pragma unroll
      for (int r = 0; r < 4; ++r)
        store_gx(gx + (base + lk*4 + r)*16 + lr, acc[mi][ni][r] + bv);
    }
  }
}

// ======================= recurrent (block-local, no inter-block sync) ====
// 16 blocks = dir(2) x group(8 of 16 batches); 13 waves of 64.
// Wave w owns cell-cols [w*32, w*32+32) for ALL 4 gates; Whh slice lives in
// 416 VGPRs/lane (104 us8 frags), loop-invariant. h ping-pongs in LDS.
// One barrier per step. Zero cross-block communication.
template<typename GXT, bool LAST>
__global__ __launch_bounds__(832, 1) void lstm_rec2(
    const GXT* __restrict__ gx,
    const unsigned short* __restrict__ whhp2,  // [2][13][104][64] us8
    const int* __restrict__ lens,
    unsigned short* __restrict__ xn,           // [T][128][832] bf16 (or unused)
    float* __restrict__ out)                   // [T][128][800] f32 (or unused)
{
  extern __shared__ char smem[];
  unsigned short* HB = (unsigned short*)smem;            // [2][16][HROW]
  float* GXL = (float*)(smem + GXL_OFF);                 // [13][32][64]

  const int tid = threadIdx.x;
  const int w = tid >> 6, l = tid & 63;
  const int li = l & 15, lq = l >> 4;
  const int dir = blockIdx.x & 1, grp = blockIdx.x >> 1;

  // Whh B-fragments -> registers (loop-invariant)
  us8 Bf[104];
  {
    const unsigned short* bsrc = whhp2 + ((size_t)(dir*13 + w)*104*64 + l)*8;
    #pragma unroll
    for (int fi = 0; fi < 104; ++fi)
      Bf[fi] = *(const us8*)(bsrc + (size_t)fi*512);
  }
  // zero h buffers
  for (int i = tid; i < 2*16*HROW/2; i += 832)
    ((unsigned*)HB)[i] = 0u;

  const int grp_len = lens[grp*16];
  int len_r[4];
  #pragma unroll
  for (int r = 0; r < 4; ++r) len_r[r] = lens[grp*16 + lq*4 + r];
  float cs[8];
  #pragma unroll
  for (int j = 0; j < 8; ++j) cs[j] = 0.f;
  __syncthreads();

  int par = 0;
  for (int s = 0; s < T_; ++s){
    const int t = dir ? (T_ - 1 - s) : s;
    if (t >= grp_len) continue;                 // uniform per block

    const unsigned short* hrd = HB + par*16*HROW;
    unsigned short* hwr = HB + (par^1)*16*HROW;
    const size_t gbase = (((size_t)t*8 + grp)*2 + dir)*13 + w;

    f32x4 acc[8];
    #pragma unroll
    for (int i = 0; i < 8; ++i) acc[i] = (f32x4){0.f,0.f,0.f,0.f};

    #pragma unroll
    for (int kk = 0; kk < 13; ++kk){
      const bf16x8 A = __builtin_bit_cast(bf16x8,
          *(const us8*)&hrd[li*HROW + kk*32 + lq*8]);
      #pragma unroll
      for (int gc = 0; gc < 8; ++gc)
        acc[gc] = __builtin_amdgcn_mfma_f32_16x16x32_bf16(A, Bf[gc*13 + kk], acc[gc], 0, 0, 0);
      if (kk < 8){
        // trickle 4 gx values/iter into LDS (j = g*8 + cf*4 + r)
        #pragma unroll
        for (int u = 0; u < 4; ++u){
          const int j = kk*4 + u;
          const int g = j >> 3, cf = (j >> 2) & 1, r = j & 3;
          const size_t off = (((gbase*4 + g)*2 + cf)*16 + lq*4 + r)*16 + li;
          float v;
          if constexpr (sizeof(GXT) == 4) v = ((const float*)gx)[off];
          else v = bf2f(((const unsigned short*)gx)[off]);
          GXL[(w*32 + j)*64 + l] = v;
        }
      }
    }

    // elementwise cell: lane owns cols {w*32+cf*16+li}, batches {lq*4+r}
    const float* gxl = &GXL[(size_t)w*32*64 + l];
    #pragma unroll
    for (int j = 0; j < 8; ++j){
      const int cf = j >> 2, r = j & 3;
      const int c = w*32 + cf*16 + li;
      const int bb = lq*4 + r;
      const float gi = acc[0*2 + cf][r] + gxl[(0*8 + cf*4 + r)*64];
      const float gf = acc[1*2 + cf][r] + gxl[(1*8 + cf*4 + r)*64];
      const float gg = acc[2*2 + cf][r] + gxl[(2*8 + cf*4 + r)*64];
      const float go = acc[3*2 + cf][r] + gxl[(3*8 + cf*4 + r)*64];
      const bool act = t < len_r[r];
      const float cn = sigm(gf)*cs[j] + sigm(gi)*tanh_f(gg);
      const float hn = sigm(go) * tanh_f(cn);
      if (act) cs[j] = cn;
      const float hv = act ? hn : bf2f(hrd[bb*HROW + c]);   // frozen old h
      hwr[bb*HROW + c] = f2bf(hv);
      if (act){
        const int bg = grp*16 + bb;
        if constexpr (LAST){
          if (c < H_) out[((size_t)t*B_ + bg)*800 + dir*H_ + c] = hv;
        } else {
          xn[((size_t)t*B_ + bg)*832 + dir*HP + c] = f2bf(hv);
        }
      }
    }
    __syncthreads();
    par ^= 1;
  }
}

// ======================= host side =======================
template<typename GXT>
static void run_all(void* const* din, float* out, char* ws, hipStream_t stream)
{
  const float* x      = (const float*)din[0];
  const int* lens     = (const int*)din[1];
  const float* wihf0  = (const float*)din[2];
  const float* wihf12 = (const float*)din[3];
  const float* whhf   = (const float*)din[4];
  const float* bsf    = (const float*)din[5];
  const float* wihb0  = (const float*)din[6];
  const float* wihb12 = (const float*)din[7];
  const float* whhb   = (const float*)din[8];
  const float* bsb    = (const float*)din[9];

  char* p = ws;
  auto alloc = [&](size_t n){ char* r = p; p += (n + 255) & ~(size_t)255; return r; };
  GXT* gx            = (GXT*)alloc((size_t)T_*B_*NW*sizeof(GXT));
  unsigned short* xA = (unsigned short*)alloc((size_t)T_*B_*832*2);
  unsigned short* xB = (unsigned short*)alloc((size_t)T_*B_*832*2);
  unsigned short* wihp = (unsigned short*)alloc((size_t)NW*K12P*2);
  unsigned short* whhp2 = (unsigned short*)alloc((size_t)2*13*104*64*8*2);
  float* biasp       = (float*)alloc((size_t)NW*4);

  hipMemsetAsync(out, 0, (size_t)T_*B_*800*4, stream);
  {
    size_t n = (size_t)T_*B_*K0P;
    k_conv_x0<<<dim3((unsigned)((n+255)/256)), dim3(256), 0, stream>>>(x, xA);
  }
  hipFuncSetAttribute(reinterpret_cast<const void*>(&lstm_rec2<GXT,false>),
                      hipFuncAttributeMaxDynamicSharedMemorySize, LDS2);
  hipFuncSetAttribute(reinterpret_cast<const void*>(&lstm_rec2<GXT,true>),
                      hipFuncAttributeMaxDynamicSharedMemorySize, LDS2);

  const unsigned short* xin[3] = {xA, xB, xA};
  unsigned short* xout[3] = {xB, xA, nullptr};
  const int ldas[3] = {K0P, 832, 832};
  const int Ks[3]   = {K0P, K12P, K12P};

  for (int lyr = 0; lyr < 3; ++lyr){
    const float* wf = (lyr == 0) ? wihf0 : wihf12 + (size_t)(lyr-1)*1600*800;
    const float* wb = (lyr == 0) ? wihb0 : wihb12 + (size_t)(lyr-1)*1600*800;
    {
      size_t n = (size_t)NW*Ks[lyr];
      k_prep_wih<<<dim3((unsigned)((n+255)/256)), dim3(256), 0, stream>>>(
          wf, wb, Ks[lyr], lyr ? 1 : 0, wihp);
    }
    k_prep_bias<<<dim3((NW+255)/256), dim3(256), 0, stream>>>(
        bsf + (size_t)lyr*1600, bsb + (size_t)lyr*1600, biasp);
    gemm_gx<GXT><<<dim3(26, 512), dim3(256), 0, stream>>>(
        xin[lyr], ldas[lyr], Ks[lyr], wihp, biasp, gx, lens);
    {
      size_t n = (size_t)2*13*104*64;
      k_prep_whh2<<<dim3((unsigned)((n+255)/256)), dim3(256), 0, stream>>>(
          whhf + (size_t)lyr*1600*400, whhb + (size_t)lyr*1600*400, whhp2);
    }
    if (lyr < 2)
      lstm_rec2<GXT,false><<<dim3(16), dim3(832), LDS2, stream>>>(
          gx, whhp2, lens, xout[lyr], out);
    else
      lstm_rec2<GXT,true><<<dim3(16), dim3(832), LDS2, stream>>>(
          gx, whhp2, lens, nullptr, out);
  }
}

extern "C" void kernel_launch(void* const* d_in, const int* in_sizes, int n_in,
                              void* d_out, int out_size, void* d_ws, size_t ws_size,
                              hipStream_t stream)
{
  (void)in_sizes; (void)n_in; (void)out_size;
  auto align = [](size_t n){ return (n + 255) & ~(size_t)255; };
  const size_t fixed =
      align((size_t)T_*B_*832*2) * 2 +
      align((size_t)NW*K12P*2) +
      align((size_t)2*13*104*64*8*2) +
      align((size_t)NW*4);
  const size_t need32 = align((size_t)T_*B_*NW*4) + fixed;
  const size_t need16 = align((size_t)T_*B_*NW*2) + fixed;

  if (ws_size >= need32)
    run_all<float>(d_in, (float*)d_out, (char*)d_ws, stream);
  else if (ws_size >= need16)
    run_all<unsigned short>(d_in, (float*)d_out, (char*)d_ws, stream);
  else
    hipMemsetAsync(d_out, 0, (size_t)T_*B_*800*4, stream);
}

// Round 7
// 6367.974 us; speedup vs baseline: 10.6442x; 10.6442x over previous
//
#include <hip/hip_runtime.h>
#include <stdint.h>
#include <stddef.h>

#define T_ 512
#define B_ 128
#define D_ 400
#define H_ 400
#define HP 416
#define GP 1664            // 4*HP (per-dir padded gate dim)
#define NW 3328            // both dirs stacked
#define K0P 448            // padded K for layer 0 GEMM
#define K12P 832           // padded K for layers 1,2 GEMM
#define NTILES 13          // h tiles of 32 per dir
#define NGRP 8             // batch groups of 16
#define REC_BLOCKS 208     // 2*8*13
#define PAIRS 208          // 416 cols / 2 per batch row (u64 slots)

// GC float stride
#define GC_FSTRIDE 576     // 16*36

// tagged h buffer: [16 cid][2 parity][16 batch][208 pair] u64
#define HBT_U64   ((size_t)16*2*16*PAIRS)
#define HBT_BYTES (HBT_U64*8)

// Whh register-fragment blob: [2 dir][13 tile][4 gate][2 chalf][13 kk][64 lane][8]
#define WHHR_US8  ((size_t)2*13*4*2*13*64)
#define WHHR_BYTES (WHHR_US8*8*2)

typedef __attribute__((ext_vector_type(8))) __bf16 bf16x8;
typedef __attribute__((ext_vector_type(4))) float f32x4;
typedef __attribute__((ext_vector_type(8))) unsigned short us8;

__device__ __forceinline__ unsigned short f2bf(float f){
  unsigned u = __builtin_bit_cast(unsigned, f);
  u = (u + 0x7FFFu + ((u >> 16) & 1u)) >> 16;
  return (unsigned short)u;
}
__device__ __forceinline__ float bf2f(unsigned short s){
  unsigned u = ((unsigned)s) << 16;
  return __builtin_bit_cast(float, u);
}
__device__ __forceinline__ float sigm(float x){ return 1.f / (1.f + __expf(-x)); }
__device__ __forceinline__ float tanh_f(float x){
  float ax = fabsf(x);
  float e = __expf(-2.f * ax);
  float t = (1.f - e) / (1.f + e);
  return x < 0.f ? -t : t;
}
__device__ __forceinline__ void store_gx(float* p, float v){ *p = v; }
__device__ __forceinline__ void store_gx(unsigned short* p, float v){ *p = f2bf(v); }

// agent-scope relaxed atomics == MALL-coherent accesses, NO cache maintenance
__device__ __forceinline__ void h_store_u64(unsigned long long* p, unsigned long long v){
  __hip_atomic_store(p, v, __ATOMIC_RELAXED, __HIP_MEMORY_SCOPE_AGENT);
}
__device__ __forceinline__ unsigned long long h_load_u64(const unsigned long long* p){
  return __hip_atomic_load(p, __ATOMIC_RELAXED, __HIP_MEMORY_SCOPE_AGENT);
}

// ======================= prep kernels =======================
__global__ void k_conv_x0(const float* __restrict__ x, unsigned short* __restrict__ xa){
  const size_t i = (size_t)blockIdx.x*256 + threadIdx.x;
  if (i >= (size_t)T_*B_*K0P) return;
  const int k = (int)(i % K0P);
  const size_t tb = i / K0P;
  xa[i] = f2bf(k < D_ ? x[tb*D_ + k] : 0.f);
}

__global__ void k_prep_wih(const float* __restrict__ wf, const float* __restrict__ wb,
                           int K, int mode, unsigned short* __restrict__ dst){
  const size_t i = (size_t)blockIdx.x*256 + threadIdx.x;
  if (i >= (size_t)NW*K) return;
  const int k = (int)(i % K);
  const int n = (int)(i / K);
  const int d = n / GP, ng = n % GP, g = ng / HP, r = ng % HP;
  const float* Wsrc = d ? wb : wf;
  float v = 0.f;
  if (r < H_){
    if (mode == 0){                       // layer 0: K real 400
      if (k < D_) v = Wsrc[(size_t)(g*H_ + r)*D_ + k];
    } else {                              // layers 1,2: [fwd400|pad16|bwd400|pad16]
      int ks = (k < 400) ? k : ((k >= 416 && k < 816) ? (k - 16) : -1);
      if (ks >= 0) v = Wsrc[(size_t)(g*H_ + r)*800 + ks];
    }
  }
  dst[i] = f2bf(v);
}

// Whh -> per-(dir,tile,gate,chalf) MFMA B-fragments, lane layout matching
// R4's WhhL[(w*32 + lr)*424 + lk*8 + kk*32] read (verified convention):
// lane l holds col c = tile*32 + ch*16 + (l&15), k = kk*32 + (l>>4)*8 + e.
__global__ void k_prep_whhR(const float* __restrict__ wf, const float* __restrict__ wb,
                            unsigned short* __restrict__ dst){
  const size_t i = (size_t)blockIdx.x*256 + threadIdx.x;
  if (i >= WHHR_US8) return;
  const int lane = (int)(i & 63);
  size_t q = i >> 6;
  const int kk = (int)(q % 13); q /= 13;
  const int ch = (int)(q % 2);  q /= 2;
  const int w  = (int)(q % 4);  q /= 4;
  const int tile = (int)(q % 13);
  const int dirx = (int)(q / 13);
  const int c  = tile*32 + ch*16 + (lane & 15);
  const int k0 = kk*32 + (lane >> 4)*8;
  const float* W = dirx ? wb : wf;
  unsigned short v[8];
  #pragma unroll
  for (int e = 0; e < 8; ++e){
    const int k = k0 + e;
    const float x = (c < H_ && k < H_) ? W[(size_t)(w*H_ + c)*H_ + k] : 0.f;
    v[e] = f2bf(x);
  }
  *(us8*)(dst + i*8) = *(const us8*)v;
}

__global__ void k_prep_bias(const float* __restrict__ bsf, const float* __restrict__ bsb,
                            float* __restrict__ dst){
  const int n = blockIdx.x*256 + threadIdx.x;
  if (n >= NW) return;
  const int d = n / GP, ng = n % GP, g = ng / HP, r = ng % HP;
  dst[n] = (r < H_) ? (d ? bsb : bsf)[g*H_ + r] : 0.f;
}

// ======================= gx GEMM (R4 verbatim) =======================
template<typename GXT>
__global__ __launch_bounds__(256) void gemm_gx(
    const unsigned short* __restrict__ X, int lda, int K,
    const unsigned short* __restrict__ W,
    const float* __restrict__ bias,
    GXT* __restrict__ gx,
    const int* __restrict__ lens)
{
  const int t = blockIdx.y;
  if (t >= lens[0]) return;
  const int n0 = blockIdx.x * 128;
  __shared__ unsigned short As[128*64];
  __shared__ unsigned short Bs[128*64];
  const int tid = threadIdx.x;
  const int l = tid & 63;
  const int w = tid >> 6;
  const int wm = (w >> 1) * 64, wn = (w & 1) * 64;
  const int lr = l & 15, lk = l >> 4;
  f32x4 acc[4][4];
  #pragma unroll
  for (int i = 0; i < 4; ++i)
    #pragma unroll
    for (int j = 0; j < 4; ++j) acc[i][j] = (f32x4){0.f,0.f,0.f,0.f};

  const unsigned short* Xb = X + (size_t)t * B_ * lda;
  const int r_ = tid >> 3, s_ = (tid & 7) * 8;

  for (int k0 = 0; k0 < K; k0 += 64){
    us8 va[4], vb[4];
    #pragma unroll
    for (int i = 0; i < 4; ++i){
      const int r = i*32 + r_;
      va[i] = *(const us8*)(Xb + (size_t)r*lda + k0 + s_);
      vb[i] = *(const us8*)(W  + (size_t)(n0 + r)*K + k0 + s_);
    }
    __syncthreads();
    #pragma unroll
    for (int i = 0; i < 4; ++i){
      const int r = i*32 + r_;
      *(us8*)&As[r*64 + s_] = va[i];
      *(us8*)&Bs[r*64 + s_] = vb[i];
    }
    __syncthreads();
    #pragma unroll
    for (int kk = 0; kk < 2; ++kk){
      bf16x8 af[4], bfr[4];
      #pragma unroll
      for (int mi = 0; mi < 4; ++mi)
        af[mi] = __builtin_bit_cast(bf16x8, *(const us8*)&As[(wm + mi*16 + lr)*64 + kk*32 + lk*8]);
      #pragma unroll
      for (int ni = 0; ni < 4; ++ni)
        bfr[ni] = __builtin_bit_cast(bf16x8, *(const us8*)&Bs[(wn + ni*16 + lr)*64 + kk*32 + lk*8]);
      #pragma unroll
      for (int mi = 0; mi < 4; ++mi)
        #pragma unroll
        for (int ni = 0; ni < 4; ++ni)
          acc[mi][ni] = __builtin_amdgcn_mfma_f32_16x16x32_bf16(af[mi], bfr[ni], acc[mi][ni], 0, 0, 0);
    }
  }
  #pragma unroll
  for (int ni = 0; ni < 4; ++ni){
    const int col = n0 + wn + ni*16 + lr;
    const float bv = bias[col];
    #pragma unroll
    for (int mi = 0; mi < 4; ++mi){
      #pragma unroll
      for (int r = 0; r < 4; ++r){
        const int b = wm + mi*16 + lk*4 + r;
        store_gx(gx + ((size_t)t*B_ + b)*NW + col, acc[mi][ni][r] + bv);
      }
    }
  }
}

// ======================= recurrent (cooperative; R4 + register-Whh) ======
// grid: 208 blocks = dir(2) x group(8 of 16 batches) x htile(13 of 32 cols)
// wave w (of 4) owns gate w; its 26 Whh B-fragments live in 104 VGPRs
// (loop-invariant) instead of LDS -> no WhhL ds_reads, no 16-way conflicts.
// h exchange: tagged u64 {2x bf16, step tag} via MALL relaxed atomics
// (fire-and-forget producers, per-line tag-retry consumers) — R4 verbatim.
template<typename GXT, bool LAST>
__global__ __launch_bounds__(256, 1) void lstm_rec(
    const GXT* __restrict__ gx,
    const unsigned short* __restrict__ whhR,   // [2][13][4][2][13][64][8] bf16
    const int* __restrict__ lens,
    unsigned long long* hbt,                   // tagged h (host-zeroed)
    unsigned short* __restrict__ xn,           // [T][128][832] bf16 (or unused)
    float* __restrict__ out)                   // [T][128][800] f32 (or unused)
{
  __shared__ unsigned short HS[16*424];        // 13568 B
  __shared__ float GC[4*GC_FSTRIDE];           // 9216 B
  __shared__ float GXS[16*132];                // 8448 B

  const int tid = threadIdx.x;
  const int bid = blockIdx.x;
  const int dir  = bid / 104;
  const int rem  = bid % 104;
  const int grp  = rem / NTILES;
  const int tile = rem % NTILES;
  const int l  = tid & 63;
  const int w  = tid >> 6;
  const int lr = l & 15;
  const int lk = l >> 4;
  const int cid = dir*NGRP + grp;

  // Whh B-fragments -> 104 VGPRs (loop-invariant)
  us8 Bf0[13], Bf1[13];
  {
    const unsigned short* bs =
        whhR + ((size_t)((dir*13 + tile)*4 + w)*2*13*64 + l)*8;
    #pragma unroll
    for (int kk = 0; kk < 13; ++kk)
      Bf0[kk] = *(const us8*)(bs + (size_t)kk*512);
    const unsigned short* bs1 = bs + (size_t)13*64*8;
    #pragma unroll
    for (int kk = 0; kk < 13; ++kk)
      Bf1[kk] = *(const us8*)(bs1 + (size_t)kk*512);
  }
  const int grp_len = lens[grp*16];          // lens sorted desc -> group max
  const int eb  = tid & 15;                  // elementwise batch
  const int p2  = tid >> 4;                  // col pair within tile
  const int mylen = lens[grp*16 + eb];
  float cs0 = 0.f, cs1 = 0.f, hs0 = 0.f, hs1 = 0.f;
  __syncthreads();

  int s_a = 0;                               // active-step counter (group-uniform)
  const int pb = tid >> 4, q = tid & 15, qg = q >> 2, qj = (q & 3) * 8;
  unsigned long long* const myslot =
      hbt + (((size_t)cid*2)*16 + eb)*PAIRS + tile*16 + p2;

  for (int s = 0; s < T_; ++s){
    const int t = dir ? (T_ - 1 - s) : s;
    if (t >= grp_len) continue;            // whole group idle: uniform skip

    // prefetch gx for this step (in flight during tag-wait)
    f32x4 pfa, pfb;
    {
      const size_t goff = ((size_t)t*B_ + grp*16 + pb) * NW + (size_t)dir*GP + qg*HP + tile*32 + qj;
      if constexpr (sizeof(GXT) == 4){
        const float* gp = (const float*)gx + goff;
        pfa = *(const f32x4*)gp;
        pfb = *(const f32x4*)(gp + 4);
      } else {
        us8 v = *(const us8*)((const unsigned short*)gx + goff);
        pfa = (f32x4){bf2f(v[0]), bf2f(v[1]), bf2f(v[2]), bf2f(v[3])};
        pfb = (f32x4){bf2f(v[4]), bf2f(v[5]), bf2f(v[6]), bf2f(v[7])};
      }
    }

    // ---- stage h (16x416) -> LDS with per-line tag validation ----
    {
      const unsigned rtag = (unsigned)s_a;
      const unsigned long long* hb =
          hbt + ((size_t)(cid*2 + (s_a & 1))*16)*PAIRS;   // [16][208] linear
      unsigned long long v[13];
      #pragma unroll
      for (int j = 0; j < 13; ++j)
        v[j] = h_load_u64(hb + j*256 + tid);
      unsigned stale = 0;
      #pragma unroll
      for (int j = 0; j < 13; ++j)
        if ((unsigned)(v[j] >> 32) != rtag) stale |= 1u << j;
      while (stale){
        const unsigned m = stale;
        #pragma unroll
        for (int j = 0; j < 13; ++j)
          if (m & (1u << j)) v[j] = h_load_u64(hb + j*256 + tid);
        #pragma unroll
        for (int j = 0; j < 13; ++j)
          if ((m & (1u << j)) && (unsigned)(v[j] >> 32) == rtag) stale &= ~(1u << j);
      }
      #pragma unroll
      for (int j = 0; j < 13; ++j){
        const int idx = j*256 + tid;
        const int b = idx / PAIRS, p = idx % PAIRS;
        *(unsigned*)&HS[b*424 + 2*p] = (unsigned)v[j];
      }
    }
    __syncthreads();

    // gates[16 x 32] for gate w: h(16x416) @ Whh_tile^T, B from registers
    f32x4 a0 = (f32x4){0.f,0.f,0.f,0.f}, a1 = (f32x4){0.f,0.f,0.f,0.f};
    {
      const int ab = lr*424 + lk*8;
      #pragma unroll
      for (int kk = 0; kk < 13; ++kk){
        bf16x8 av = __builtin_bit_cast(bf16x8, *(const us8*)&HS[ab + kk*32]);
        a0 = __builtin_amdgcn_mfma_f32_16x16x32_bf16(av, Bf0[kk], a0, 0, 0, 0);
        a1 = __builtin_amdgcn_mfma_f32_16x16x32_bf16(av, Bf1[kk], a1, 0, 0, 0);
      }
    }
    // publish gate partials + gx to LDS
    {
      float* Gw = GC + w * GC_FSTRIDE;
      #pragma unroll
      for (int r = 0; r < 4; ++r){
        Gw[(lk*4 + r)*36 + lr]      = a0[r];
        Gw[(lk*4 + r)*36 + 16 + lr] = a1[r];
      }
      float* gp = GXS + pb*132 + qg*32 + qj;
      *(f32x4*)gp = pfa;
      *(f32x4*)(gp + 4) = pfb;
    }
    __syncthreads();

    // elementwise LSTM cell: thread owns (b=eb, cols {2*p2, 2*p2+1})
    const bool act = t < mylen;
    const int c0 = 2*p2, c1 = 2*p2 + 1;
    {
      const float gi0 = GC[0*GC_FSTRIDE + eb*36 + c0] + GXS[eb*132 + c0];
      const float gf0 = GC[1*GC_FSTRIDE + eb*36 + c0] + GXS[eb*132 + 32 + c0];
      const float gg0 = GC[2*GC_FSTRIDE + eb*36 + c0] + GXS[eb*132 + 64 + c0];
      const float go0 = GC[3*GC_FSTRIDE + eb*36 + c0] + GXS[eb*132 + 96 + c0];
      const float gi1 = GC[0*GC_FSTRIDE + eb*36 + c1] + GXS[eb*132 + c1];
      const float gf1 = GC[1*GC_FSTRIDE + eb*36 + c1] + GXS[eb*132 + 32 + c1];
      const float gg1 = GC[2*GC_FSTRIDE + eb*36 + c1] + GXS[eb*132 + 64 + c1];
      const float go1 = GC[3*GC_FSTRIDE + eb*36 + c1] + GXS[eb*132 + 96 + c1];
      const float cn0 = sigm(gf0)*cs0 + sigm(gi0)*tanh_f(gg0);
      const float hn0 = sigm(go0) * tanh_f(cn0);
      const float cn1 = sigm(gf1)*cs1 + sigm(gi1)*tanh_f(gg1);
      const float hn1 = sigm(go1) * tanh_f(cn1);
      if (act){ cs0 = cn0; hs0 = hn0; cs1 = cn1; hs1 = hn1; }
    }
    // publish tagged h (frozen value if masked) into next parity slot
    {
      const unsigned hu = (unsigned)f2bf(hs0) | ((unsigned)f2bf(hs1) << 16);
      const unsigned long long hv =
          (unsigned long long)hu | ((unsigned long long)(unsigned)(s_a + 1) << 32);
      h_store_u64(myslot + ((size_t)((s_a + 1) & 1))*16*PAIRS, hv);
    }
    if (act){
      const int bg = grp*16 + eb;
      const int hc = tile*32 + c0;
      if constexpr (LAST){
        float* op = out + ((size_t)t*B_ + bg)*800 + dir*H_ + hc;
        if (hc < H_)     op[0] = hs0;
        if (hc + 1 < H_) op[1] = hs1;
      } else {
        const unsigned hu = (unsigned)f2bf(hs0) | ((unsigned)f2bf(hs1) << 16);
        *(unsigned*)(xn + ((size_t)t*B_ + bg)*832 + (size_t)dir*HP + hc) = hu;
      }
    }
    ++s_a;
  }
}

// ======================= host side =======================
template<typename GXT>
static void run_all(void* const* din, float* out, char* ws, hipStream_t stream)
{
  const float* x      = (const float*)din[0];
  const int* lens     = (const int*)din[1];
  const float* wihf0  = (const float*)din[2];
  const float* wihf12 = (const float*)din[3];
  const float* whhf   = (const float*)din[4];
  const float* bsf    = (const float*)din[5];
  const float* wihb0  = (const float*)din[6];
  const float* wihb12 = (const float*)din[7];
  const float* whhb   = (const float*)din[8];
  const float* bsb    = (const float*)din[9];

  char* p = ws;
  auto alloc = [&](size_t n){ char* r = p; p += (n + 255) & ~(size_t)255; return r; };
  GXT* gx            = (GXT*)alloc((size_t)T_*B_*NW*sizeof(GXT));
  unsigned short* xA = (unsigned short*)alloc((size_t)T_*B_*832*2);
  unsigned short* xB = (unsigned short*)alloc((size_t)T_*B_*832*2);
  unsigned short* wihp = (unsigned short*)alloc((size_t)NW*K12P*2);
  unsigned short* whhR = (unsigned short*)alloc(WHHR_BYTES);
  float* biasp       = (float*)alloc((size_t)NW*4);
  unsigned long long* hbt = (unsigned long long*)alloc(HBT_BYTES);

  hipMemsetAsync(out, 0, (size_t)T_*B_*800*4, stream);
  {
    size_t n = (size_t)T_*B_*K0P;
    k_conv_x0<<<dim3((unsigned)((n+255)/256)), dim3(256), 0, stream>>>(x, xA);
  }

  const unsigned short* xin[3] = {xA, xB, xA};
  unsigned short* xout[3] = {xB, xA, nullptr};
  const int ldas[3] = {K0P, 832, 832};
  const int Ks[3]   = {K0P, K12P, K12P};

  for (int lyr = 0; lyr < 3; ++lyr){
    const float* wf = (lyr == 0) ? wihf0 : wihf12 + (size_t)(lyr-1)*1600*800;
    const float* wb = (lyr == 0) ? wihb0 : wihb12 + (size_t)(lyr-1)*1600*800;
    {
      size_t n = (size_t)NW*Ks[lyr];
      k_prep_wih<<<dim3((unsigned)((n+255)/256)), dim3(256), 0, stream>>>(
          wf, wb, Ks[lyr], lyr ? 1 : 0, wihp);
    }
    k_prep_bias<<<dim3((NW+255)/256), dim3(256), 0, stream>>>(
        bsf + (size_t)lyr*1600, bsb + (size_t)lyr*1600, biasp);
    gemm_gx<GXT><<<dim3(26, 512), dim3(256), 0, stream>>>(
        xin[lyr], ldas[lyr], Ks[lyr], wihp, biasp, gx, lens);
    {
      size_t n = WHHR_US8;
      k_prep_whhR<<<dim3((unsigned)((n+255)/256)), dim3(256), 0, stream>>>(
          whhf + (size_t)lyr*1600*400, whhb + (size_t)lyr*1600*400, whhR);
    }
    hipMemsetAsync(hbt, 0, HBT_BYTES, stream);

    const GXT* a_gx = gx;
    const unsigned short* a_whhR = whhR;
    const int* a_lens = lens;
    unsigned long long* a_hbt = hbt;
    unsigned short* a_xn = xout[lyr];
    float* a_out = out;
    void* args[6] = {&a_gx, &a_whhR, &a_lens, &a_hbt, &a_xn, &a_out};
    if (lyr < 2)
      hipLaunchCooperativeKernel(reinterpret_cast<const void*>(&lstm_rec<GXT,false>),
                                 dim3(REC_BLOCKS), dim3(256), args, 0, stream);
    else
      hipLaunchCooperativeKernel(reinterpret_cast<const void*>(&lstm_rec<GXT,true>),
                                 dim3(REC_BLOCKS), dim3(256), args, 0, stream);
  }
}

extern "C" void kernel_launch(void* const* d_in, const int* in_sizes, int n_in,
                              void* d_out, int out_size, void* d_ws, size_t ws_size,
                              hipStream_t stream)
{
  (void)in_sizes; (void)n_in; (void)out_size;
  auto align = [](size_t n){ return (n + 255) & ~(size_t)255; };
  const size_t fixed =
      align((size_t)T_*B_*832*2) * 2 +
      align((size_t)NW*K12P*2) +
      align(WHHR_BYTES) +
      align((size_t)NW*4) +
      align(HBT_BYTES);
  const size_t need32 = align((size_t)T_*B_*NW*4) + fixed;
  const size_t need16 = align((size_t)T_*B_*NW*2) + fixed;

  if (ws_size >= need32)
    run_all<float>(d_in, (float*)d_out, (char*)d_ws, stream);
  else if (ws_size >= need16)
    run_all<unsigned short>(d_in, (float*)d_out, (char*)d_ws, stream);
  else
    hipMemsetAsync(d_out, 0, (size_t)T_*B_*800*4, stream);
}